// Round 2
// baseline (2054.805 us; speedup 1.0000x reference)
//
#include <hip/hip_runtime.h>
#include <hip/hip_bf16.h>

typedef __bf16 bf16;
typedef __attribute__((ext_vector_type(8))) __bf16 bf16x8;
typedef __attribute__((ext_vector_type(4))) float floatx4;

// Problem constants: B=8, N=4096, DM=1024, H=16, G=4, D=64; rows = B*N = 32768
// All d_in are FLOAT32 (per reference). Compute in bf16 MFMA, output fp32.
// qkv buffer layout: [row][3072] = q(0..1023) | k(1024..2047) | v(2048..3071), bf16

// ---------------- weight transpose + fp32->bf16: dst[C][R] = (bf16)src[R][C] ----------------
__global__ __launch_bounds__(256)
void transpose_cvt_kernel(const float* __restrict__ src, bf16* __restrict__ dst, int R, int C) {
    size_t i = (size_t)blockIdx.x * 256 + threadIdx.x;
    if (i >= (size_t)R * C) return;
    int c = (int)(i / R);
    int r = (int)(i % R);
    dst[(size_t)c * R + r] = (bf16)src[(size_t)r * C + c];
}

// ---------------- qkv bias concat (fp32) ----------------
__global__ __launch_bounds__(256)
void biaspack_kernel(const float* __restrict__ bq, const float* __restrict__ bk,
                     const float* __restrict__ bv, float* __restrict__ out) {
    int i = blockIdx.x * 256 + threadIdx.x;   // 3072 total
    float v;
    if (i < 1024)      v = bq[i];
    else if (i < 2048) v = bk[i - 1024];
    else               v = bv[i - 2048];
    out[i] = v;
}

// ---------------- GEMM: C[M][Nc] = A[M][K] @ WT[Nc][K]^T + bias ----------------
// BM=128 fixed. Waves: 2 in M, WN in N (wave tile 64x64 via 4x4 mfma 16x16x32).
// AF32: A operand is fp32 in global (converted to bf16 during LDS staging).
// EPI: 0 = bf16 out (bias)
//      1 = f32 out (bias)
//      2 = f32 out ((x+bias)/8 + mask[row])   mask fp32
//      3 = f32 out (x + bias + qadd[row][col])  qadd bf16
template<int BN, int WN, int EPI, bool AF32>
__global__ __launch_bounds__(WN * 128)
void gemm_kernel(const void* __restrict__ Av, int lda,
                 const bf16* __restrict__ WT,
                 const float* __restrict__ bias,
                 void* __restrict__ Cout, int ldc,
                 const float* __restrict__ mask,
                 const bf16* __restrict__ qadd, int ldq,
                 int K) {
    constexpr int BM = 128;
    constexpr int BK = 32;
    constexpr int NT = WN * 128;
    __shared__ bf16 As[BM][BK + 8];
    __shared__ bf16 Bs[BN][BK + 8];

    const int tid  = threadIdx.x;
    const int wid  = tid >> 6;
    const int lane = tid & 63;
    const int l16  = lane & 15;
    const int quad = lane >> 4;
    const int wm   = wid & 1;
    const int wn   = wid >> 1;
    const int m0   = blockIdx.x * BM;
    const int n0   = blockIdx.y * BN;

    floatx4 acc[4][4];
#pragma unroll
    for (int i = 0; i < 4; i++)
#pragma unroll
        for (int j = 0; j < 4; j++) acc[i][j] = (floatx4)0.0f;

    for (int k0 = 0; k0 < K; k0 += BK) {
        __syncthreads();
        for (int i = tid; i < BM * 4; i += NT) {
            int r = i >> 2, cg = (i & 3) * 8;
            if (AF32) {
                const float* ap = (const float*)Av + (size_t)(m0 + r) * lda + k0 + cg;
                float4 x = *(const float4*)ap;
                float4 y = *(const float4*)(ap + 4);
                bf16x8 o;
                o[0] = (bf16)x.x; o[1] = (bf16)x.y; o[2] = (bf16)x.z; o[3] = (bf16)x.w;
                o[4] = (bf16)y.x; o[5] = (bf16)y.y; o[6] = (bf16)y.z; o[7] = (bf16)y.w;
                *(bf16x8*)&As[r][cg] = o;
            } else {
                *(bf16x8*)&As[r][cg] =
                    *(const bf16x8*)((const bf16*)Av + (size_t)(m0 + r) * lda + k0 + cg);
            }
        }
        for (int i = tid; i < BN * 4; i += NT) {
            int r = i >> 2, cg = (i & 3) * 8;
            *(bf16x8*)&Bs[r][cg] = *(const bf16x8*)(WT + (size_t)(n0 + r) * K + k0 + cg);
        }
        __syncthreads();
        bf16x8 af[4], bfv[4];
#pragma unroll
        for (int mi = 0; mi < 4; mi++)
            af[mi] = *(const bf16x8*)&As[wm * 64 + mi * 16 + l16][quad * 8];
#pragma unroll
        for (int ni = 0; ni < 4; ni++)
            bfv[ni] = *(const bf16x8*)&Bs[wn * 64 + ni * 16 + l16][quad * 8];
#pragma unroll
        for (int mi = 0; mi < 4; mi++)
#pragma unroll
            for (int ni = 0; ni < 4; ni++)
                acc[mi][ni] = __builtin_amdgcn_mfma_f32_16x16x32_bf16(
                    af[mi], bfv[ni], acc[mi][ni], 0, 0, 0);
    }

#pragma unroll
    for (int mi = 0; mi < 4; mi++) {
#pragma unroll
        for (int ni = 0; ni < 4; ni++) {
            int col  = n0 + wn * 64 + ni * 16 + l16;
            int rowb = m0 + wm * 64 + mi * 16 + quad * 4;
            float bv = bias[col];
#pragma unroll
            for (int e = 0; e < 4; e++) {
                int row = rowb + e;
                float v = acc[mi][ni][e] + bv;
                if (EPI == 0) {
                    ((bf16*)Cout)[(size_t)row * ldc + col] = (bf16)v;
                } else if (EPI == 1) {
                    ((float*)Cout)[(size_t)row * ldc + col] = v;
                } else if (EPI == 2) {
                    ((float*)Cout)[(size_t)row * ldc + col] = v * 0.125f + mask[row];
                } else {
                    v += (float)qadd[(size_t)row * ldq + col];
                    ((float*)Cout)[(size_t)row * ldc + col] = v;
                }
            }
        }
    }
}

// ---------------- softmax over n for qs: qw[b*64+hg][n] ----------------
__global__ __launch_bounds__(256)
void softmax_kernel(const float* __restrict__ qa, const float* __restrict__ mask,
                    float* __restrict__ qw) {
    int bh = blockIdx.x;           // b*64 + hg
    int b = bh >> 6, hg = bh & 63;
    int tid = threadIdx.x;
    float xs[16];
    float mx = -1e30f;
#pragma unroll
    for (int j = 0; j < 16; j++) {
        int n = tid + j * 256;
        float x = qa[((size_t)(b * 4096 + n)) * 64 + hg] * 0.125f + mask[b * 4096 + n];
        xs[j] = x;
        mx = fmaxf(mx, x);
    }
    __shared__ float red[256];
    red[tid] = mx;
    __syncthreads();
    for (int s = 128; s > 0; s >>= 1) {
        if (tid < s) red[tid] = fmaxf(red[tid], red[tid + s]);
        __syncthreads();
    }
    mx = red[0];
    __syncthreads();
    float sum = 0.f;
#pragma unroll
    for (int j = 0; j < 16; j++) { xs[j] = __expf(xs[j] - mx); sum += xs[j]; }
    red[tid] = sum;
    __syncthreads();
    for (int s = 128; s > 0; s >>= 1) {
        if (tid < s) red[tid] += red[tid + s];
        __syncthreads();
    }
    float inv = 1.0f / red[0];
#pragma unroll
    for (int j = 0; j < 16; j++)
        qw[(size_t)bh * 4096 + tid + j * 256] = xs[j] * inv;
}

// ---------------- gq: gmax/gmin[bh*64+d] = max/min_g sum_n qw[bhg][n]*q[b,n,h,d] ----------------
__global__ __launch_bounds__(256)
void gq_kernel(const float* __restrict__ qw, const bf16* __restrict__ qkv,
               float* __restrict__ gmax, float* __restrict__ gmin) {
    int bh = blockIdx.x;          // b*16 + h
    int b = bh >> 4, h = bh & 15;
    int tid = threadIdx.x;
    int g = tid >> 6, d = tid & 63;
    const float* wrow = qw + ((size_t)(b * 64 + h * 4 + g)) * 4096;
    const bf16* qcol  = qkv + (size_t)(b * 4096) * 3072 + h * 64 + d;
    float a0 = 0, a1 = 0, a2 = 0, a3 = 0;
    for (int n = 0; n < 1024; n++) {
        a0 += wrow[n]        * (float)qcol[(size_t)n * 3072];
        a1 += wrow[n + 1024] * (float)qcol[(size_t)(n + 1024) * 3072];
        a2 += wrow[n + 2048] * (float)qcol[(size_t)(n + 2048) * 3072];
        a3 += wrow[n + 3072] * (float)qcol[(size_t)(n + 3072) * 3072];
    }
    __shared__ float sg[4][64];
    sg[g][d] = a0 + a1 + a2 + a3;
    __syncthreads();
    if (tid < 64) {
        float mx = sg[0][tid], mn = sg[0][tid];
#pragma unroll
        for (int gg = 1; gg < 4; gg++) {
            mx = fmaxf(mx, sg[gg][tid]);
            mn = fminf(mn, sg[gg][tid]);
        }
        gmax[bh * 64 + tid] = mx;
        gmin[bh * 64 + tid] = mn;
    }
}

// ---------------- gk: same but scalars from ksc[row][64] (no softmax) ----------------
__global__ __launch_bounds__(256)
void gk_kernel(const float* __restrict__ ksc, const bf16* __restrict__ qkv,
               float* __restrict__ gmax, float* __restrict__ gmin) {
    int bh = blockIdx.x;
    int b = bh >> 4, h = bh & 15;
    int tid = threadIdx.x;
    int g = tid >> 6, d = tid & 63;
    int hg = h * 4 + g;
    const float* sbase = ksc + (size_t)(b * 4096) * 64 + hg;
    const bf16* kcol   = qkv + (size_t)(b * 4096) * 3072 + 1024 + h * 64 + d;
    float a0 = 0, a1 = 0, a2 = 0, a3 = 0;
    for (int n = 0; n < 1024; n++) {
        a0 += sbase[(size_t)n * 64]          * (float)kcol[(size_t)n * 3072];
        a1 += sbase[(size_t)(n + 1024) * 64] * (float)kcol[(size_t)(n + 1024) * 3072];
        a2 += sbase[(size_t)(n + 2048) * 64] * (float)kcol[(size_t)(n + 2048) * 3072];
        a3 += sbase[(size_t)(n + 3072) * 64] * (float)kcol[(size_t)(n + 3072) * 3072];
    }
    __shared__ float sg[4][64];
    sg[g][d] = a0 + a1 + a2 + a3;
    __syncthreads();
    if (tid < 64) {
        float mx = sg[0][tid], mn = sg[0][tid];
#pragma unroll
        for (int gg = 1; gg < 4; gg++) {
            mx = fmaxf(mx, sg[gg][tid]);
            mn = fminf(mn, sg[gg][tid]);
        }
        gmax[bh * 64 + tid] = mx;
        gmin[bh * 64 + tid] = mn;
    }
}

// ---------------- elementwise: dst[row][c] = x>=0 ? x*gmax : x*gmin (bf16 in/out) ----------------
__global__ __launch_bounds__(256)
void maxg_kernel(const bf16* __restrict__ qkv, int coloff,
                 const float* __restrict__ gmax, const float* __restrict__ gmin,
                 bf16* __restrict__ dst) {
    size_t i8 = (size_t)blockIdx.x * 256 + threadIdx.x;
    size_t e0 = i8 * 8;
    int row = (int)(e0 >> 10);
    int c   = (int)(e0 & 1023);
    int b   = row >> 12;
    bf16x8 kv = *(const bf16x8*)(qkv + (size_t)row * 3072 + coloff + c);
    bf16x8 out;
#pragma unroll
    for (int j = 0; j < 8; j++) {
        float f  = (float)kv[j];
        float gm = gmax[b * 1024 + c + j];
        float gn = gmin[b * 1024 + c + j];
        out[j] = (bf16)(f >= 0.f ? f * gm : f * gn);
    }
    *(bf16x8*)(dst + e0) = out;
}

extern "C" void kernel_launch(void* const* d_in, const int* in_sizes, int n_in,
                              void* d_out, int out_size, void* d_ws, size_t ws_size,
                              hipStream_t stream) {
    const float* hs   = (const float*)d_in[0];
    const float* mask = (const float*)d_in[1];
    const float* Wq   = (const float*)d_in[2];
    const float* bq   = (const float*)d_in[3];
    const float* Wqa  = (const float*)d_in[4];
    const float* bqa  = (const float*)d_in[5];
    const float* Wk   = (const float*)d_in[6];
    const float* bk   = (const float*)d_in[7];
    const float* Wka  = (const float*)d_in[8];
    const float* bka  = (const float*)d_in[9];
    const float* Wv   = (const float*)d_in[10];
    const float* bv   = (const float*)d_in[11];
    const float* Wt   = (const float*)d_in[12];
    const float* bt   = (const float*)d_in[13];

    char* p = (char*)d_ws;
    auto alloc = [&](size_t bytes) {
        char* r = p;
        p += (bytes + 255) & ~(size_t)255;
        return (void*)r;
    };
    bf16*  WqkvT = (bf16*) alloc((size_t)3072 * 1024 * 2);
    bf16*  WqaT  = (bf16*) alloc((size_t)64 * 1024 * 2);
    bf16*  WkaT  = (bf16*) alloc((size_t)64 * 1024 * 2);
    bf16*  WtT   = (bf16*) alloc((size_t)1024 * 1024 * 2);
    float* biasf = (float*)alloc((size_t)3072 * 4);
    bf16*  qkv   = (bf16*) alloc((size_t)32768 * 3072 * 2);
    float* qa    = (float*)alloc((size_t)32768 * 64 * 4);
    float* qw    = (float*)alloc((size_t)512 * 4096 * 4);
    float* gqmax = (float*)alloc((size_t)8192 * 4);
    float* gqmin = (float*)alloc((size_t)8192 * 4);
    bf16*  qk_u  = (bf16*) alloc((size_t)32768 * 1024 * 2);  // qk, later reused as u
    float* ksc   = (float*)alloc((size_t)32768 * 64 * 4);
    float* gkmax = (float*)alloc((size_t)8192 * 4);
    float* gkmin = (float*)alloc((size_t)8192 * 4);

    // weight prep (fp32 -> bf16, transposed to [out][in])
    transpose_cvt_kernel<<<4096, 256, 0, stream>>>(Wq, WqkvT, 1024, 1024);
    transpose_cvt_kernel<<<4096, 256, 0, stream>>>(Wk, WqkvT + (size_t)1024 * 1024, 1024, 1024);
    transpose_cvt_kernel<<<4096, 256, 0, stream>>>(Wv, WqkvT + (size_t)2048 * 1024, 1024, 1024);
    transpose_cvt_kernel<<<256, 256, 0, stream>>>(Wqa, WqaT, 1024, 64);
    transpose_cvt_kernel<<<256, 256, 0, stream>>>(Wka, WkaT, 1024, 64);
    transpose_cvt_kernel<<<4096, 256, 0, stream>>>(Wt, WtT, 1024, 1024);
    biaspack_kernel<<<12, 256, 0, stream>>>(bq, bk, bv, biasf);

    // qkv = hs @ [Wq|Wk|Wv] + bias   (M=32768, N=3072, K=1024); A fp32 converted in staging
    gemm_kernel<128, 2, 0, true><<<dim3(256, 24), 256, 0, stream>>>(
        hs, 1024, WqkvT, biasf, qkv, 3072, nullptr, nullptr, 0, 1024);
    // qa = q @ Wqa + bqa  (f32 out)
    gemm_kernel<64, 1, 1, false><<<dim3(256, 1), 128, 0, stream>>>(
        qkv, 3072, WqaT, bqa, qa, 64, nullptr, nullptr, 0, 1024);
    // qw = softmax(qa/8 + mask) over n
    softmax_kernel<<<512, 256, 0, stream>>>(qa, mask, qw);
    // gq max/min over g
    gq_kernel<<<128, 256, 0, stream>>>(qw, qkv, gqmax, gqmin);
    // qk elementwise from k
    maxg_kernel<<<16384, 256, 0, stream>>>(qkv, 1024, gqmax, gqmin, qk_u);
    // ksc = (qk @ Wka + bka)/8 + mask   (f32 out)
    gemm_kernel<64, 1, 2, false><<<dim3(256, 1), 128, 0, stream>>>(
        qk_u, 1024, WkaT, bka, ksc, 64, mask, nullptr, 0, 1024);
    // gk max/min over g
    gk_kernel<<<128, 256, 0, stream>>>(ksc, qkv, gkmax, gkmin);
    // u elementwise from v (reuse qk buffer)
    maxg_kernel<<<16384, 256, 0, stream>>>(qkv, 2048, gkmax, gkmin, qk_u);
    // out = u @ Wt + bt + q   (fp32 out)
    gemm_kernel<128, 2, 3, false><<<dim3(256, 8), 256, 0, stream>>>(
        qk_u, 1024, WtT, bt, d_out, 1024, nullptr, qkv, 3072, 1024);
}

// Round 3
// 996.949 us; speedup vs baseline: 2.0611x; 2.0611x over previous
//
#include <hip/hip_runtime.h>
#include <hip/hip_bf16.h>

typedef __bf16 bf16;
typedef __attribute__((ext_vector_type(8))) __bf16 bf16x8;
typedef __attribute__((ext_vector_type(4))) float floatx4;

// B=8, N=4096, DM=1024, H=16, G=4, D=64; rows = 32768
// Inputs fp32; compute bf16 MFMA; output fp32.
// qkv layout: [row][3200] = q(0..1023)|k(1024..2047)|v(2048..3071)|qa(3072..3135)|pad

__device__ __forceinline__ void gload_lds16(const void* g, void* l) {
    __builtin_amdgcn_global_load_lds(
        (const __attribute__((address_space(1))) unsigned int*)g,
        (__attribute__((address_space(3))) unsigned int*)l, 16, 0, 0);
}

// ---------------- fp32 -> bf16 convert (8 elems/thread) ----------------
__global__ __launch_bounds__(256)
void cvt_kernel(const float* __restrict__ src, bf16* __restrict__ dst, int n8) {
    int i8 = blockIdx.x * 256 + threadIdx.x;
    if (i8 >= n8) return;
    const float* s = src + (size_t)i8 * 8;
    float4 x = *(const float4*)s;
    float4 y = *(const float4*)(s + 4);
    bf16x8 o;
    o[0] = (bf16)x.x; o[1] = (bf16)x.y; o[2] = (bf16)x.z; o[3] = (bf16)x.w;
    o[4] = (bf16)y.x; o[5] = (bf16)y.y; o[6] = (bf16)y.z; o[7] = (bf16)y.w;
    *(bf16x8*)(dst + (size_t)i8 * 8) = o;
}

// ---------------- LDS-tiled transpose+cvt: dst[C][R] = (bf16)src[R][C] ----------------
__global__ __launch_bounds__(256)
void transpose_cvt_kernel(const float* __restrict__ src, bf16* __restrict__ dst, int R, int C) {
    __shared__ bf16 tile[64][65];
    int tr0 = blockIdx.x * 64;   // row tile in src
    int tc0 = blockIdx.y * 64;   // col tile in src
    int tx = threadIdx.x & 63, ty = threadIdx.x >> 6;
#pragma unroll
    for (int j = 0; j < 16; j++) {
        int r = ty + j * 4;
        tile[tx][r] = (bf16)src[(size_t)(tr0 + r) * C + tc0 + tx];
    }
    __syncthreads();
#pragma unroll
    for (int j = 0; j < 16; j++) {
        int r = ty + j * 4;
        dst[(size_t)(tc0 + r) * R + tr0 + tx] = tile[r][tx];
    }
}

// ---------------- bias pack: biasf[0..3071]=bq|bk|bv, [3072..3199]=0, zbias[0..1023]=0 ----
__global__ __launch_bounds__(256)
void biaspack_kernel(const float* __restrict__ bq, const float* __restrict__ bk,
                     const float* __restrict__ bv, float* __restrict__ biasf,
                     float* __restrict__ zbias) {
    int i = blockIdx.x * 256 + threadIdx.x;
    if (i < 1024)      biasf[i] = bq[i];
    else if (i < 2048) biasf[i] = bk[i - 1024];
    else if (i < 3072) biasf[i] = bv[i - 2048];
    else if (i < 3200) biasf[i] = 0.f;
    else if (i < 4224) zbias[i - 3200] = 0.f;
}

// ---------------- composite bias: biasf[3072+j] = dot(bq, Wqa[:,j]) + bqa[j] ----------------
__global__ __launch_bounds__(64)
void compbias_kernel(const float* __restrict__ bq, const float* __restrict__ Wqa,
                     const float* __restrict__ bqa, float* __restrict__ out) {
    int j = threadIdx.x;
    float a = 0.f;
    for (int t = 0; t < 1024; t++) a += bq[t] * Wqa[(size_t)t * 64 + j];
    out[j] = a + bqa[j];
}

// ---------------- GEMM: C[M][Nc] = A[M][K] @ WT[Nc][K]^T + bias (m97 structure) ----------
// BM=128, BK=32, packed LDS, global_load_lds width=16.
// EPI: 0 = bf16 out (+bias)
//      2 = f32 out ((x+bias)*0.125 + mask[row])
//      3 = f32 out (x + bias + qadd[row][col])   qadd bf16
template<int BN, int WN, int EPI>
__global__ __launch_bounds__(WN * 128)
void gemm_kernel(const bf16* __restrict__ A, int lda,
                 const bf16* __restrict__ WT,
                 const float* __restrict__ bias,
                 void* __restrict__ Cout, int ldc,
                 const float* __restrict__ mask,
                 const bf16* __restrict__ qadd, int ldq,
                 int K) {
    constexpr int BM = 128;
    constexpr int NT = WN * 128;
    __shared__ bf16 As[BM * 32];
    __shared__ bf16 Bs[BN * 32];

    const int tid  = threadIdx.x;
    const int wid  = tid >> 6;
    const int lane = tid & 63;
    const int l16  = lane & 15;
    const int quad = lane >> 4;
    const int wm   = wid & 1;
    const int wn   = wid >> 1;
    const int m0   = blockIdx.x * BM;
    const int n0   = blockIdx.y * BN;

    floatx4 acc[4][4];
#pragma unroll
    for (int i = 0; i < 4; i++)
#pragma unroll
        for (int j = 0; j < 4; j++) acc[i][j] = (floatx4)0.0f;

    for (int k0 = 0; k0 < K; k0 += 32) {
        __syncthreads();
#pragma unroll
        for (int i = tid; i < BM * 4; i += NT) {
            const bf16* gp = A + (size_t)(m0 + (i >> 2)) * lda + k0 + (i & 3) * 8;
            gload_lds16(gp, (char*)As + (size_t)(i & ~63) * 16);
        }
#pragma unroll
        for (int i = tid; i < BN * 4; i += NT) {
            const bf16* gp = WT + (size_t)(n0 + (i >> 2)) * K + k0 + (i & 3) * 8;
            gload_lds16(gp, (char*)Bs + (size_t)(i & ~63) * 16);
        }
        __syncthreads();
        bf16x8 af[4], bfv[4];
#pragma unroll
        for (int mi = 0; mi < 4; mi++)
            af[mi] = *(const bf16x8*)&As[(wm * 64 + mi * 16 + l16) * 32 + quad * 8];
#pragma unroll
        for (int ni = 0; ni < 4; ni++)
            bfv[ni] = *(const bf16x8*)&Bs[(wn * 64 + ni * 16 + l16) * 32 + quad * 8];
#pragma unroll
        for (int mi = 0; mi < 4; mi++)
#pragma unroll
            for (int ni = 0; ni < 4; ni++)
                acc[mi][ni] = __builtin_amdgcn_mfma_f32_16x16x32_bf16(
                    af[mi], bfv[ni], acc[mi][ni], 0, 0, 0);
    }

#pragma unroll
    for (int mi = 0; mi < 4; mi++) {
#pragma unroll
        for (int ni = 0; ni < 4; ni++) {
            int col  = n0 + wn * 64 + ni * 16 + l16;
            int rowb = m0 + wm * 64 + mi * 16 + quad * 4;
            float bv = bias[col];
#pragma unroll
            for (int e = 0; e < 4; e++) {
                int row = rowb + e;
                float v = acc[mi][ni][e] + bv;
                if (EPI == 0) {
                    ((bf16*)Cout)[(size_t)row * ldc + col] = (bf16)v;
                } else if (EPI == 2) {
                    ((float*)Cout)[(size_t)row * ldc + col] = v * 0.125f + mask[row];
                } else {
                    v += (float)qadd[(size_t)row * ldq + col];
                    ((float*)Cout)[(size_t)row * ldc + col] = v;
                }
            }
        }
    }
}

// ---------------- softmax over n: qw[b*64+hg][n], logits = qa(bf16 in qkv)*0.125+mask ----
__global__ __launch_bounds__(256)
void softmax_kernel(const bf16* __restrict__ qkv, const float* __restrict__ mask,
                    float* __restrict__ qw) {
    int bh = blockIdx.x;           // b*64 + hg
    int b = bh >> 6, hg = bh & 63;
    int tid = threadIdx.x;
    float xs[16];
    float mx = -1e30f;
#pragma unroll
    for (int j = 0; j < 16; j++) {
        int n = tid + j * 256;
        float x = (float)qkv[(size_t)(b * 4096 + n) * 3200 + 3072 + hg] * 0.125f
                  + mask[b * 4096 + n];
        xs[j] = x;
        mx = fmaxf(mx, x);
    }
    __shared__ float red[256];
    red[tid] = mx;
    __syncthreads();
    for (int s = 128; s > 0; s >>= 1) {
        if (tid < s) red[tid] = fmaxf(red[tid], red[tid + s]);
        __syncthreads();
    }
    mx = red[0];
    __syncthreads();
    float sum = 0.f;
#pragma unroll
    for (int j = 0; j < 16; j++) { xs[j] = __expf(xs[j] - mx); sum += xs[j]; }
    red[tid] = sum;
    __syncthreads();
    for (int s = 128; s > 0; s >>= 1) {
        if (tid < s) red[tid] += red[tid + s];
        __syncthreads();
    }
    float inv = 1.0f / red[0];
#pragma unroll
    for (int j = 0; j < 16; j++)
        qw[(size_t)bh * 4096 + tid + j * 256] = xs[j] * inv;
}

// ---------------- gq stage1: partial[bh][ch][g][d] = sum_{n in chunk} qw*q ----------------
__global__ __launch_bounds__(256)
void gq1_kernel(const float* __restrict__ qw, const bf16* __restrict__ qkv,
                float* __restrict__ part) {
    int bh = blockIdx.x, ch = blockIdx.y;
    int b = bh >> 4, h = bh & 15;
    int tid = threadIdx.x;
    int g = tid >> 6, d = tid & 63;
    const float* wrow = qw + ((size_t)(b * 64 + h * 4 + g)) * 4096 + ch * 256;
    const bf16* qcol  = qkv + (size_t)(b * 4096 + ch * 256) * 3200 + h * 64 + d;
    float a = 0.f;
#pragma unroll 8
    for (int n = 0; n < 256; n++)
        a += wrow[n] * (float)qcol[(size_t)n * 3200];
    part[(((size_t)bh * 16 + ch) * 4 + g) * 64 + d] = a;
}

// ---------------- gk stage1: scalars from ksc[row][64] ----------------
__global__ __launch_bounds__(256)
void gk1_kernel(const float* __restrict__ ksc, const bf16* __restrict__ qkv,
                float* __restrict__ part) {
    int bh = blockIdx.x, ch = blockIdx.y;
    int b = bh >> 4, h = bh & 15;
    int tid = threadIdx.x;
    int g = tid >> 6, d = tid & 63;
    const float* sbase = ksc + (size_t)(b * 4096 + ch * 256) * 64 + h * 4 + g;
    const bf16* kcol   = qkv + (size_t)(b * 4096 + ch * 256) * 3200 + 1024 + h * 64 + d;
    float a = 0.f;
#pragma unroll 8
    for (int n = 0; n < 256; n++)
        a += sbase[(size_t)n * 64] * (float)kcol[(size_t)n * 3200];
    part[(((size_t)bh * 16 + ch) * 4 + g) * 64 + d] = a;
}

// ---------------- stage2: sum 16 chunks, then max/min over g ----------------
__global__ __launch_bounds__(256)
void gred_kernel(const float* __restrict__ part,
                 float* __restrict__ gmax, float* __restrict__ gmin) {
    int bh = blockIdx.x;
    int tid = threadIdx.x;
    int g = tid >> 6, d = tid & 63;
    float a = 0.f;
#pragma unroll
    for (int c = 0; c < 16; c++)
        a += part[(((size_t)bh * 16 + c) * 4 + g) * 64 + d];
    __shared__ float sg[4][64];
    sg[g][d] = a;
    __syncthreads();
    if (tid < 64) {
        float mx = sg[0][tid], mn = sg[0][tid];
#pragma unroll
        for (int gg = 1; gg < 4; gg++) {
            mx = fmaxf(mx, sg[gg][tid]);
            mn = fminf(mn, sg[gg][tid]);
        }
        gmax[bh * 64 + tid] = mx;
        gmin[bh * 64 + tid] = mn;
    }
}

// ---------------- elementwise: dst[row][c] = x>=0 ? x*gmax : x*gmin ----------------
__global__ __launch_bounds__(256)
void maxg_kernel(const bf16* __restrict__ qkv, int coloff,
                 const float* __restrict__ gmax, const float* __restrict__ gmin,
                 bf16* __restrict__ dst) {
    size_t i8 = (size_t)blockIdx.x * 256 + threadIdx.x;
    size_t e0 = i8 * 8;
    int row = (int)(e0 >> 10);
    int c   = (int)(e0 & 1023);
    int b   = row >> 12;
    bf16x8 kv = *(const bf16x8*)(qkv + (size_t)row * 3200 + coloff + c);
    bf16x8 out;
#pragma unroll
    for (int j = 0; j < 8; j++) {
        float f  = (float)kv[j];
        float gm = gmax[b * 1024 + c + j];
        float gn = gmin[b * 1024 + c + j];
        out[j] = (bf16)(f >= 0.f ? f * gm : f * gn);
    }
    *(bf16x8*)(dst + e0) = out;
}

extern "C" void kernel_launch(void* const* d_in, const int* in_sizes, int n_in,
                              void* d_out, int out_size, void* d_ws, size_t ws_size,
                              hipStream_t stream) {
    const float* hs   = (const float*)d_in[0];
    const float* mask = (const float*)d_in[1];
    const float* Wq   = (const float*)d_in[2];
    const float* bq   = (const float*)d_in[3];
    const float* Wqa  = (const float*)d_in[4];
    const float* bqa  = (const float*)d_in[5];
    const float* Wk   = (const float*)d_in[6];
    const float* bk   = (const float*)d_in[7];
    const float* Wka  = (const float*)d_in[8];
    const float* bka  = (const float*)d_in[9];
    const float* Wv   = (const float*)d_in[10];
    const float* bv   = (const float*)d_in[11];
    const float* Wt   = (const float*)d_in[12];
    const float* bt   = (const float*)d_in[13];

    char* p = (char*)d_ws;
    auto alloc = [&](size_t bytes) {
        char* r = p;
        p += (bytes + 255) & ~(size_t)255;
        return (void*)r;
    };
    bf16*  WT    = (bf16*) alloc((size_t)3200 * 1024 * 2);  // [Wq|Wk|Wv|comp|pad]^T rows x K
    bf16*  WqBf  = (bf16*) alloc((size_t)1024 * 1024 * 2);  // Wq as stored, bf16
    bf16*  WqaT  = (bf16*) alloc((size_t)128 * 1024 * 2);   // 128 rows (64 real + pad)
    bf16*  WkaT  = (bf16*) alloc((size_t)64 * 1024 * 2);
    bf16*  WtT   = (bf16*) alloc((size_t)1024 * 1024 * 2);
    float* biasf = (float*)alloc((size_t)3200 * 4);
    float* zbias = (float*)alloc((size_t)1024 * 4);
    bf16*  qkv   = (bf16*) alloc((size_t)32768 * 3200 * 2);
    bf16*  hsb   = (bf16*) alloc((size_t)32768 * 1024 * 2); // aliased later as qk_u
    float* qw    = (float*)alloc((size_t)512 * 4096 * 4);   // aliased later as ksc
    float* part  = (float*)alloc((size_t)128 * 16 * 256 * 4);
    float* gqmax = (float*)alloc((size_t)8192 * 4);
    float* gqmin = (float*)alloc((size_t)8192 * 4);
    float* gkmax = (float*)alloc((size_t)8192 * 4);
    float* gkmin = (float*)alloc((size_t)8192 * 4);
    bf16*  qk_u  = hsb;            // hs_bf16 dead after QKV GEMM
    float* ksc   = qw;             // qw dead after gq stage1

    // --- prep ---
    cvt_kernel<<<16384, 256, 0, stream>>>(hs, hsb, 4194304);
    cvt_kernel<<<512, 256, 0, stream>>>(Wq, WqBf, 131072);
    transpose_cvt_kernel<<<dim3(16, 16), 256, 0, stream>>>(Wq, WT, 1024, 1024);
    transpose_cvt_kernel<<<dim3(16, 16), 256, 0, stream>>>(Wk, WT + (size_t)1024 * 1024, 1024, 1024);
    transpose_cvt_kernel<<<dim3(16, 16), 256, 0, stream>>>(Wv, WT + (size_t)2048 * 1024, 1024, 1024);
    transpose_cvt_kernel<<<dim3(16, 1), 256, 0, stream>>>(Wqa, WqaT, 1024, 64);
    transpose_cvt_kernel<<<dim3(16, 1), 256, 0, stream>>>(Wka, WkaT, 1024, 64);
    transpose_cvt_kernel<<<dim3(16, 16), 256, 0, stream>>>(Wt, WtT, 1024, 1024);
    biaspack_kernel<<<17, 256, 0, stream>>>(bq, bk, bv, biasf, zbias);
    compbias_kernel<<<1, 64, 0, stream>>>(bq, Wqa, bqa, biasf + 3072);
    // comp^T[j][k] = sum_t WqaT[j][t] * WqBf[k][t]  -> WT rows 3072..3199 (rows>=64 junk, unused)
    gemm_kernel<128, 2, 0><<<dim3(1, 8), 256, 0, stream>>>(
        WqaT, 1024, WqBf, zbias, WT + (size_t)3072 * 1024, 1024, nullptr, nullptr, 0, 1024);

    // --- main pipeline ---
    // qkv|qa = hsb @ WT^T + biasf  (M=32768, N=3200, K=1024)
    gemm_kernel<128, 2, 0><<<dim3(256, 25), 256, 0, stream>>>(
        hsb, 1024, WT, biasf, qkv, 3200, nullptr, nullptr, 0, 1024);
    softmax_kernel<<<512, 256, 0, stream>>>(qkv, mask, qw);
    gq1_kernel<<<dim3(128, 16), 256, 0, stream>>>(qw, qkv, part);
    gred_kernel<<<128, 256, 0, stream>>>(part, gqmax, gqmin);
    maxg_kernel<<<16384, 256, 0, stream>>>(qkv, 1024, gqmax, gqmin, qk_u);
    // ksc = (qk @ Wka + bka)*0.125 + mask
    gemm_kernel<64, 1, 2><<<dim3(256, 1), 128, 0, stream>>>(
        qk_u, 1024, WkaT, bka, ksc, 64, mask, nullptr, 0, 1024);
    gk1_kernel<<<dim3(128, 16), 256, 0, stream>>>(ksc, qkv, part);
    gred_kernel<<<128, 256, 0, stream>>>(part, gkmax, gkmin);
    maxg_kernel<<<16384, 256, 0, stream>>>(qkv, 2048, gkmax, gkmin, qk_u);
    // out = u @ Wt + bt + q
    gemm_kernel<128, 2, 3><<<dim3(256, 8), 256, 0, stream>>>(
        qk_u, 1024, WtT, bt, d_out, 1024, nullptr, qkv, 3200, 1024);
}